// Round 8
// baseline (115.080 us; speedup 1.0000x reference)
//
#include <hip/hip_runtime.h>

static constexpr int CH   = 128;   // CHANNELS
static constexpr int KW   = 160;   // W row length (bf16): 128 tok + wc0,wc1,b1 + pad
static constexpr int KPAD = 192;   // Atile row length (bf16) -> 384B rows

typedef __attribute__((ext_vector_type(8))) short bf16x8;
typedef __attribute__((ext_vector_type(4))) float f32x4;

__device__ inline unsigned short f2bf(float x) {
    unsigned int u = __float_as_uint(x);
    unsigned int r = (u + 0x7fffu + ((u >> 16) & 1u)) >> 16;  // RNE
    return (unsigned short)r;
}
__device__ inline unsigned int pack2bf(float a, float b) {
    return (unsigned int)f2bf(a) | ((unsigned int)f2bf(b) << 16);
}
__device__ inline float bf2f(unsigned short v) {
    return __uint_as_float((unsigned int)v << 16);
}

// ---------------------------------------------------------------------------
// Detect whether edge_index arrived as int64 (JAX x64 on) or int32 (x64 off).
// ---------------------------------------------------------------------------
__global__ void detect_idx64(const unsigned int* __restrict__ idxw,
                             int* __restrict__ flag) {
    const int t = threadIdx.x;
    unsigned int nz = 0;
    for (int i = t; i < 128; i += 64) nz |= idxw[2 * i + 1];
    unsigned long long b = __ballot(nz != 0u);
    if (t == 0) flag[0] = (b == 0ULL) ? 1 : 0;
}

// ---------------------------------------------------------------------------
// idxp[e] = src | (dst<<16).  (N = 50000 < 65536 so u16 each.)
// ---------------------------------------------------------------------------
__global__ __launch_bounds__(256) void idx_prep(
    const unsigned int* __restrict__ idxw, unsigned int* __restrict__ idxp,
    int E, const int* __restrict__ flag) {
    const int is64 = flag[0];
    const int stride = gridDim.x * 256;
    for (int i = blockIdx.x * 256 + threadIdx.x; i < E; i += stride) {
        const unsigned s = is64 ? idxw[2 * i] : idxw[i];
        const unsigned d = is64 ? idxw[2 * (E + i)] : idxw[E + i];
        idxp[i] = s | (d << 16);
    }
}

// ---------------------------------------------------------------------------
// W[c][k] (bf16, [256][KW]): k<128 tok-weights; k=128/129 = +-wc0/wc1;
// k=130 = b1 (Q only); rest 0.
// ---------------------------------------------------------------------------
__global__ __launch_bounds__(192) void w1_prep(const float* __restrict__ w1,
                                               const float* __restrict__ b1,
                                               unsigned short* __restrict__ W) {
    const int c = blockIdx.x;    // 0..255
    const int k = threadIdx.x;
    if (k >= KW) return;
    const bool isQ = c >= 128;
    const int cc = c & 127;
    float v;
    if (k < 128)       v = isQ ? w1[(size_t)(128 + k) * CH + cc]
                               : w1[(size_t)k * CH + cc];
    else if (k == 128) v = (isQ ? 1.f : -1.f) * w1[(size_t)(2 * CH) * CH + cc];
    else if (k == 129) v = (isQ ? 1.f : -1.f) * w1[(size_t)(2 * CH + 1) * CH + cc];
    else if (k == 130) v = isQ ? b1[cc] : 0.f;
    else               v = 0.f;
    W[(size_t)c * KW + k] = f2bf(v);
}

// ---------------------------------------------------------------------------
// Node stage: 32 nodes x 256 cols per block, swapped-operand MFMA, K=160
// (coords+bias folded). Stores P/Q in CHUNKED layout:
//   Pc[(chunk*N + node)*16 + (c&15)], chunk = c>>4  (same for Qc).
// ---------------------------------------------------------------------------
__global__ __launch_bounds__(256) void node_mfma3(
    const float* __restrict__ tokens, const float* __restrict__ coords,
    const unsigned short* __restrict__ W, unsigned short* __restrict__ Pc,
    unsigned short* __restrict__ Qc, int N) {
    __shared__ unsigned short Atile[32 * KPAD];  // 12 KB, XOR-swizzled rows

    const int t    = threadIdx.x;
    const int l    = t & 63;
    const int wid  = t >> 6;
    const int n0   = blockIdx.x * 32;
    const int woff = wid * 64;
    const int bl   = l & 15;
    const int bh   = l >> 4;

    // token chunks: 32 nodes x 16 chunks of 16B
#pragma unroll
    for (int it = 0; it < 2; ++it) {
        const int idx  = it * 256 + t;
        const int node = idx >> 4;
        const int cq   = idx & 15;
        float4 v0 = make_float4(0.f, 0.f, 0.f, 0.f);
        float4 v1 = v0;
        if (n0 + node < N) {
            const float* src = &tokens[(size_t)(n0 + node) * CH + cq * 8];
            v0 = *(const float4*)src;
            v1 = *(const float4*)(src + 4);
        }
        uint4 u;
        u.x = pack2bf(v0.x, v0.y);
        u.y = pack2bf(v0.z, v0.w);
        u.z = pack2bf(v1.x, v1.y);
        u.w = pack2bf(v1.z, v1.w);
        const int byte = node * 384 + ((cq * 16) ^ ((node & 7) << 4));
        *(uint4*)((char*)Atile + byte) = u;
    }
    // ext chunks: k=128..191 -> (cx, cy, 1, 0, ...)
    {
        const int node = t >> 3;
        const int ce   = t & 7;
        uint4 u = make_uint4(0u, 0u, 0u, 0u);
        if (ce == 0 && n0 + node < N) {
            const float cx = coords[2 * (n0 + node)];
            const float cy = coords[2 * (n0 + node) + 1];
            u.x = pack2bf(cx, cy);
            u.y = pack2bf(1.f, 0.f);
        }
        const int byte = node * 384 + (((16 + ce) * 16) ^ ((node & 7) << 4));
        *(uint4*)((char*)Atile + byte) = u;
    }
    __syncthreads();

    f32x4 acc[4][2];
#pragma unroll
    for (int m = 0; m < 4; ++m)
#pragma unroll
        for (int n = 0; n < 2; ++n) acc[m][n] = (f32x4){0.f, 0.f, 0.f, 0.f};

#pragma unroll
    for (int ks = 0; ks < 5; ++ks) {
        bf16x8 wfrag[4], tfrag[2];
#pragma unroll
        for (int m = 0; m < 4; ++m)
            wfrag[m] = *(const bf16x8*)&W[(size_t)(woff + m * 16 + bl) * KW +
                                          ks * 32 + bh * 8];
#pragma unroll
        for (int n = 0; n < 2; ++n) {
            const int row  = n * 16 + bl;
            const int byte = row * 384 + ((ks * 64 + bh * 16) ^ ((row & 7) << 4));
            tfrag[n] = *(const bf16x8*)((const char*)Atile + byte);
        }
#pragma unroll
        for (int m = 0; m < 4; ++m)
#pragma unroll
            for (int n = 0; n < 2; ++n)
                acc[m][n] = __builtin_amdgcn_mfma_f32_16x16x32_bf16(
                    wfrag[m], tfrag[n], acc[m][n], 0, 0, 0);
    }

#pragma unroll
    for (int m = 0; m < 4; ++m) {
        const int c = woff + m * 16 + bh * 4;    // output col 0..255
        const int cc = c & (CH - 1);
        unsigned short* base = (c < CH ? Pc : Qc) +
                               (size_t)(cc >> 4) * N * 16 + (cc & 15);
#pragma unroll
        for (int n = 0; n < 2; ++n) {
            const int node = n0 + n * 16 + bl;
            if (node < N) {
                uint2 val;
                val.x = pack2bf(acc[m][n][0], acc[m][n][1]);
                val.y = pack2bf(acc[m][n][2], acc[m][n][3]);
                *(uint2*)&base[(size_t)node * 16] = val;
            }
        }
    }
}

// ---------------------------------------------------------------------------
// dot over 8 channels: relu(p+q) . wv[0..7]  (p,q are 8 packed bf16)
// ---------------------------------------------------------------------------
__device__ inline float dot8(uint4 p, uint4 q, const float* wv) {
    float acc = 0.f;
    const unsigned pw[4] = {p.x, p.y, p.z, p.w};
    const unsigned qw[4] = {q.x, q.y, q.z, q.w};
#pragma unroll
    for (int i = 0; i < 4; ++i) {
        const float plo = __uint_as_float(pw[i] << 16);
        const float phi = __uint_as_float(pw[i] & 0xffff0000u);
        const float qlo = __uint_as_float(qw[i] << 16);
        const float qhi = __uint_as_float(qw[i] & 0xffff0000u);
        acc = fmaf(fmaxf(plo + qlo, 0.f), wv[2 * i], acc);
        acc = fmaf(fmaxf(phi + qhi, 0.f), wv[2 * i + 1], acc);
    }
    return acc;
}

// ---------------------------------------------------------------------------
// Channel-chunked edge partials. chunk = blockIdx%8 (XCD round-robin pin);
// chunk working set = P-chunk + Q-chunk = 3.2 MB < 4 MiB L2 -> gathers hit L2.
// One thread = one edge's full 16-ch partial (32B row gathers, no reduce).
// idx loads + partial stores nontemporal to keep L2 for the chunk.
// ---------------------------------------------------------------------------
template <typename PT>
__global__ __launch_bounds__(256) void edge_partial(
    const unsigned int* __restrict__ idxp, const unsigned short* __restrict__ Pc,
    const unsigned short* __restrict__ Qc, const float* __restrict__ w2,
    PT* __restrict__ partial, int N, int E) {
    const int chunk = blockIdx.x & 7;
    const int tid_c = (int)(blockIdx.x >> 3) * 256 + threadIdx.x;
    const int nthr  = (int)(gridDim.x >> 3) * 256;
    float wv[16];
#pragma unroll
    for (int i = 0; i < 16; ++i) wv[i] = w2[chunk * 16 + i];
    const unsigned short* Pb = Pc + (size_t)chunk * N * 16;
    const unsigned short* Qb = Qc + (size_t)chunk * N * 16;
    PT* po = partial + (size_t)chunk * E;

    for (int e = tid_c; e < E; e += 2 * nthr) {
        const int eB = e + nthr;
        const bool okB = eB < E;
        const unsigned pkA = __builtin_nontemporal_load(&idxp[e]);
        const unsigned pkB = okB ? __builtin_nontemporal_load(&idxp[eB]) : 0u;
        const uint4* prA = (const uint4*)(Pb + (size_t)(pkA & 0xffffu) * 16);
        const uint4* qrA = (const uint4*)(Qb + (size_t)(pkA >> 16) * 16);
        const uint4* prB = (const uint4*)(Pb + (size_t)(pkB & 0xffffu) * 16);
        const uint4* qrB = (const uint4*)(Qb + (size_t)(pkB >> 16) * 16);
        const uint4 a0 = prA[0], a1 = prA[1];
        const uint4 b0 = qrA[0], b1 = qrA[1];
        uint4 c0, c1, d0, d1;
        if (okB) { c0 = prB[0]; c1 = prB[1]; d0 = qrB[0]; d1 = qrB[1]; }

        const float vA = dot8(a0, b0, wv) + dot8(a1, b1, wv + 8);
        if constexpr (sizeof(PT) == 2)
            __builtin_nontemporal_store(f2bf(vA), &po[e]);
        else
            __builtin_nontemporal_store(vA, &po[e]);
        if (okB) {
            const float vB = dot8(c0, d0, wv) + dot8(c1, d1, wv + 8);
            if constexpr (sizeof(PT) == 2)
                __builtin_nontemporal_store(f2bf(vB), &po[eB]);
            else
                __builtin_nontemporal_store(vB, &po[eB]);
        }
    }
}

// ---------------------------------------------------------------------------
// out[e] = sum_c partial[c][e] + b2.  Thread per 4 edges (float4 store).
// ---------------------------------------------------------------------------
template <typename PT>
__global__ __launch_bounds__(256) void edge_reduce(
    const PT* __restrict__ partial, const float* __restrict__ b2,
    float* __restrict__ out, int E) {
    const int nq = E >> 2;
    const float bias = b2[0];
    const int stride = gridDim.x * 256;
    for (int q = blockIdx.x * 256 + threadIdx.x; q < nq; q += stride) {
        const int e = q * 4;
        float s0 = bias, s1 = bias, s2 = bias, s3 = bias;
#pragma unroll
        for (int c = 0; c < 8; ++c) {
            if constexpr (sizeof(PT) == 2) {
                const ushort4 v = *(const ushort4*)&partial[(size_t)c * E + e];
                s0 += bf2f(v.x); s1 += bf2f(v.y); s2 += bf2f(v.z); s3 += bf2f(v.w);
            } else {
                const float4 v = *(const float4*)&partial[(size_t)c * E + e];
                s0 += v.x; s1 += v.y; s2 += v.z; s3 += v.w;
            }
        }
        *(float4*)&out[e] = make_float4(s0, s1, s2, s3);
    }
    // tail (E not multiple of 4)
    if (blockIdx.x == 0 && threadIdx.x < (E & 3)) {
        const int e = (E & ~3) + threadIdx.x;
        float s = bias;
#pragma unroll
        for (int c = 0; c < 8; ++c) {
            if constexpr (sizeof(PT) == 2) s += bf2f(partial[(size_t)c * E + e]);
            else                           s += partial[(size_t)c * E + e];
        }
        out[e] = s;
    }
}

extern "C" void kernel_launch(void* const* d_in, const int* in_sizes, int n_in,
                              void* d_out, int out_size, void* d_ws,
                              size_t ws_size, hipStream_t stream) {
    const float* tokens = (const float*)d_in[0];
    const float* coords = (const float*)d_in[1];
    const unsigned int* idxw = (const unsigned int*)d_in[2];
    const float* w1 = (const float*)d_in[3];
    const float* b1 = (const float*)d_in[4];
    const float* w2 = (const float*)d_in[5];
    const float* b2 = (const float*)d_in[6];
    float* out = (float*)d_out;

    const int N = in_sizes[0] / CH;       // 50000
    const int E = (int)(in_sizes[2] / 2); // 800000

    unsigned short* Pc = (unsigned short*)d_ws;
    unsigned short* Qc = Pc + (size_t)N * CH;
    unsigned int* idxp = (unsigned int*)(Qc + (size_t)N * CH);
    unsigned short* W = (unsigned short*)(idxp + E);
    int* flag = (int*)(W + 256 * KW);
    char* pbase = (char*)(flag + 4);  // 16B-aligned (all prior sizes are)
    const size_t used = (size_t)(pbase - (char*)d_ws);
    const bool pf32 = (used + (size_t)8 * E * sizeof(float)) <= ws_size;

    detect_idx64<<<1, 64, 0, stream>>>(idxw, flag);
    idx_prep<<<1024, 256, 0, stream>>>(idxw, idxp, E, flag);
    w1_prep<<<256, 192, 0, stream>>>(w1, b1, W);

    node_mfma3<<<(N + 31) / 32, 256, 0, stream>>>(tokens, coords, W, Pc, Qc, N);

    if (pf32) {
        float* partial = (float*)pbase;
        edge_partial<float><<<2048, 256, 0, stream>>>(idxp, Pc, Qc, w2,
                                                      partial, N, E);
        edge_reduce<float><<<784, 256, 0, stream>>>(partial, b2, out, E);
    } else {
        unsigned short* partial = (unsigned short*)pbase;
        edge_partial<unsigned short><<<2048, 256, 0, stream>>>(idxp, Pc, Qc, w2,
                                                               partial, N, E);
        edge_reduce<unsigned short><<<784, 256, 0, stream>>>(partial, b2, out, E);
    }
}